// Round 7
// baseline (1573.103 us; speedup 1.0000x reference)
//
#include <hip/hip_runtime.h>
#include <hip/hip_bf16.h>

using bf16 = __hip_bfloat16;
typedef __attribute__((ext_vector_type(8))) short short8;
typedef __attribute__((ext_vector_type(4))) float f32x4;
typedef __attribute__((ext_vector_type(16))) float f32x16;

#define GAS(p) ((const __attribute__((address_space(1))) unsigned int*)(p))
#define LAS(p) ((__attribute__((address_space(3))) unsigned int*)(p))

// ---------------- cast f32 -> bf16 (vectorized) ----------------
__global__ __launch_bounds__(256)
void cast_f32_to_bf16(const float* __restrict__ in, bf16* __restrict__ out, int n) {
  const int stride = gridDim.x * blockDim.x * 4;
  for (int i = (blockIdx.x * blockDim.x + threadIdx.x) * 4; i < n; i += stride) {
    float4 v = *reinterpret_cast<const float4*>(in + i);
    bf16 b0 = __float2bfloat16(v.x);
    bf16 b1 = __float2bfloat16(v.y);
    bf16 b2 = __float2bfloat16(v.z);
    bf16 b3 = __float2bfloat16(v.w);
    ushort4 p;
    p.x = *reinterpret_cast<unsigned short*>(&b0);
    p.y = *reinterpret_cast<unsigned short*>(&b1);
    p.z = *reinterpret_cast<unsigned short*>(&b2);
    p.w = *reinterpret_cast<unsigned short*>(&b3);
    *reinterpret_cast<ushort4*>(out + i) = p;
  }
}

// ================= 256x256 NT GEMM, mfma 32x32x16, A-in-LDS / B-from-L2 ====
// C[M,N] = A[M,K]*B[N,K]^T.  512 thr (8 waves, 2M x 4N), BK=64.
// LDS: A ONLY, 2 x 32KB dbuf (rows q0=[0,64)u[128,192) at +0, q1 at +16KB;
//      j-half (+128 rows) at +8KB; 3-bit XOR swizzle on 16B-slot idx, keyed on
//      local-row bits 1-3; global source pre-swizzled (DMA dest linear)).
// B fragments: per-lane global_load_dwordx4 from L2 (W col-panel 2MB/XCD is
// L2-resident under the XCD swizzle), double-buffered in registers, issued one
// tile ahead.  Per tile: ONE vmcnt(0)+barrier (exact: all in-flight VMEM is
// this tile's data; 1-2 phase issue-to-wait distance hides latency; dbuf LDS
// => no WAR, so no second barrier).  MFMA: 32x32x16 (2495 TF ceiling), wave
// tile 128x64 = 4m x 2n frags, acc 8 x f32x16 = 128 VGPR.
template <typename OutT, bool KMASK>
__global__ __launch_bounds__(512, 2)
void gemm256(const bf16* __restrict__ A, const bf16* __restrict__ B,
             OutT* __restrict__ C, int M, int N, int K,
             const float* __restrict__ mu_q, const float* __restrict__ sigma_q,
             const float* __restrict__ eps_q,
             const float* __restrict__ mu_kv, const float* __restrict__ sigma_kv,
             const float* __restrict__ eps_kv) {
  extern __shared__ char smem[];   // 2 x 32KB A buffers

  const int nwg = gridDim.x;
  const int cpx = nwg >> 3;
  const int bid = blockIdx.x;
  const int swz = (bid & 7) * cpx + (bid >> 3);
  const int ntn = N >> 8;
  const int tm = swz / ntn, tn = swz % ntn;
  const int row0 = tm << 8, col0 = tn << 8;

  const int t = threadIdx.x;
  const int wave = t >> 6, lane = t & 63;
  const int wm = wave >> 2, wn = wave & 3;   // 2 x 4 wave grid
  const int rl = lane & 31;                  // mfma row/col within 32
  const int h  = lane >> 5;                  // k-half select
  const int ldsWave = wave << 10;

  // ---- A stage: per-thread global source (inverse swizzle) ----
  const int srow = t >> 3;                                  // local row 0..63
  const int scol = ((t & 7) * 8) ^
                   (((srow & 2) << 4) | ((srow & 4) << 2) | (srow & 8));
  size_t aRow[2][2];
#pragma unroll
  for (int q = 0; q < 2; ++q)
#pragma unroll
    for (int j = 0; j < 2; ++j)
      aRow[q][j] = (size_t)(row0 + j * 128 + q * 64 + srow) * K + scol;

  // ---- A ds_read per-lane constants (same swizzle) ----
  const int xsw = ((rl & 2) << 5) | ((rl & 4) << 3) | ((rl & 8) << 1);
  int koffA[4];
#pragma unroll
  for (int ks = 0; ks < 4; ++ks) koffA[ks] = ((ks * 32 + h * 16) ^ xsw);
  const int laneA = wm * 8192 + rl * 128;
  // frag addr = buf + (m>>1)*16384 + (m&1)*4096 + laneA + koffA[ks]

  // ---- B global fragment base (per-lane) ----
  const int bc0 = col0 + wn * 64 + rl;       // + n*32

  f32x16 acc[4][2];
#pragma unroll
  for (int m = 0; m < 4; ++m)
#pragma unroll
    for (int n = 0; n < 2; ++n) acc[m][n] = (f32x16)0.f;

#define STG_A(buf_, q_, kk_) do {                                             \
    __builtin_amdgcn_global_load_lds(GAS(A + aRow[q_][0] + (kk_)),            \
        LAS(smem + (buf_) * 32768 + (q_) * 16384 + ldsWave), 16, 0, 0);       \
    __builtin_amdgcn_global_load_lds(GAS(A + aRow[q_][1] + (kk_)),            \
        LAS(smem + (buf_) * 32768 + (q_) * 16384 + 8192 + ldsWave), 16, 0, 0);\
  } while (0)

#define LDB(dst_, kk_) do {                                                   \
    _Pragma("unroll")                                                         \
    for (int n = 0; n < 2; ++n)                                               \
      _Pragma("unroll")                                                       \
      for (int ks = 0; ks < 4; ++ks)                                          \
        dst_[n][ks] = *reinterpret_cast<const short8*>(                       \
            B + (size_t)(bc0 + n * 32) * K + (kk_) + ks * 16 + h * 8);        \
  } while (0)

  short8 bA[2][4], bB[2][4];
  const int NT = K >> 6;

  // prologue: tile 0 into buf0 / bA
  STG_A(0, 0, 0); STG_A(0, 1, 0);
  LDB(bA, 0);

#define TILE(cb_, nb_, bCur_, bNxt_, tt_) do {                                \
    const size_t kkn = (size_t)(((tt_) + 1 < NT) ? (((tt_) + 1) << 6) : 0);   \
    const char* curb = smem + (cb_) * 32768;                                  \
    /* P0: rows m0,m1 */                                                      \
    asm volatile("s_waitcnt vmcnt(0)" ::: "memory");                          \
    __builtin_amdgcn_s_barrier();                                             \
    asm volatile("" ::: "memory");                                            \
    short8 af0[2][4];                                                         \
    _Pragma("unroll")                                                         \
    for (int mm = 0; mm < 2; ++mm)                                            \
      _Pragma("unroll")                                                       \
      for (int ks = 0; ks < 4; ++ks)                                          \
        af0[mm][ks] = *reinterpret_cast<const short8*>(                       \
            curb + mm * 4096 + laneA + koffA[ks]);                            \
    STG_A(nb_, 0, kkn);                                                       \
    LDB(bNxt_, kkn);                                                          \
    __builtin_amdgcn_s_setprio(1);                                            \
    _Pragma("unroll")                                                         \
    for (int mm = 0; mm < 2; ++mm)                                            \
      _Pragma("unroll")                                                       \
      for (int n = 0; n < 2; ++n)                                             \
        _Pragma("unroll")                                                     \
        for (int ks = 0; ks < 4; ++ks)                                        \
          acc[mm][n] = __builtin_amdgcn_mfma_f32_32x32x16_bf16(               \
              af0[mm][ks], bCur_[n][ks], acc[mm][n], 0, 0, 0);                \
    __builtin_amdgcn_s_setprio(0);                                            \
    /* P1: rows m2,m3 (no barrier: dbuf, no WAR) */                           \
    short8 af1[2][4];                                                         \
    _Pragma("unroll")                                                         \
    for (int mm = 0; mm < 2; ++mm)                                            \
      _Pragma("unroll")                                                       \
      for (int ks = 0; ks < 4; ++ks)                                          \
        af1[mm][ks] = *reinterpret_cast<const short8*>(                       \
            curb + 16384 + mm * 4096 + laneA + koffA[ks]);                    \
    STG_A(nb_, 1, kkn);                                                       \
    __builtin_amdgcn_s_setprio(1);                                            \
    _Pragma("unroll")                                                         \
    for (int mm = 0; mm < 2; ++mm)                                            \
      _Pragma("unroll")                                                       \
      for (int n = 0; n < 2; ++n)                                             \
        _Pragma("unroll")                                                     \
        for (int ks = 0; ks < 4; ++ks)                                        \
          acc[2 + mm][n] = __builtin_amdgcn_mfma_f32_32x32x16_bf16(           \
              af1[mm][ks], bCur_[n][ks], acc[2 + mm][n], 0, 0, 0);            \
    __builtin_amdgcn_s_setprio(0);                                            \
  } while (0)

  for (int tt = 0; tt < NT; tt += 2) {
    TILE(0, 1, bA, bB, tt);
    TILE(1, 0, bB, bA, tt + 1);
  }
#undef TILE
#undef STG_A
#undef LDB

  asm volatile("s_waitcnt vmcnt(0)" ::: "memory");

  // ---- epilogue: 32x32 C/D layout col=lane&31, row=(reg&3)+8*(reg>>2)+4*h ----
  const int crow0 = row0 + wm * 128 + 4 * h;
  const int ccol0 = col0 + wn * 64 + rl;
  float cscale[2];
  if constexpr (KMASK) {
#pragma unroll
    for (int n = 0; n < 2; ++n) {
      const int d = (ccol0 + n * 32) & 63;
      const float a = mu_q[d] + eps_q[d] * sigma_q[d];
      const float b = mu_kv[d] + eps_kv[d] * sigma_kv[d];
      cscale[n] = 0.125f / ((1.f + __expf(-a)) * (1.f + __expf(-b)));
    }
  }
#pragma unroll
  for (int m = 0; m < 4; ++m) {
#pragma unroll
    for (int n = 0; n < 2; ++n) {
      const int cc = ccol0 + n * 32;
#pragma unroll
      for (int rg = 0; rg < 4; ++rg) {
#pragma unroll
        for (int rr = 0; rr < 4; ++rr) {
          const int row = crow0 + m * 32 + rg * 8 + rr;
          float v = acc[m][n][rg * 4 + rr];
          if constexpr (KMASK) v *= cscale[n];
          if constexpr (sizeof(OutT) == 2) {
            C[(size_t)row * N + cc] = __float2bfloat16(v);
          } else {
            C[(size_t)row * N + cc] = v;
          }
        }
      }
    }
  }
}

// ---------------- per-token cross-head attention, MFMA ----------------
__global__ __launch_bounds__(256)
void attn_mfma(const bf16* __restrict__ Q, const bf16* __restrict__ K,
               const bf16* __restrict__ V,
               const float* __restrict__ mu_kv, const float* __restrict__ sigma_kv,
               const float* __restrict__ eps_kv,
               bf16* __restrict__ AO) {
  __shared__ bf16 Vt[64][72];
  __shared__ bf16 P[4][16][72];

  const int t = threadIdx.x;
  const int wave = t >> 6, lane = t & 63;
  const int fl = lane & 15, g4 = lane >> 4;
  const int kq = g4 * 8;
  const size_t base = (size_t)blockIdx.x * 4096;

#pragma unroll
  for (int rep = 0; rep < 2; ++rep) {
    const int idx = rep * 256 + t;
    const int g = idx & 63;
    const int d0 = (idx >> 6) * 8;
    short8 v8 = *reinterpret_cast<const short8*>(&V[base + (size_t)g * 64 + d0]);
#pragma unroll
    for (int j = 0; j < 8; ++j)
      *reinterpret_cast<short*>(&Vt[d0 + j][g]) = (short)v8[j];
  }

  short8 aq[2];
#pragma unroll
  for (int ks = 0; ks < 2; ++ks)
    aq[ks] = *reinterpret_cast<const short8*>(
        &Q[base + (size_t)(wave * 16 + fl) * 64 + ks * 32 + kq]);
  short8 bk[4][2];
#pragma unroll
  for (int n = 0; n < 4; ++n)
#pragma unroll
    for (int ks = 0; ks < 2; ++ks)
      bk[n][ks] = *reinterpret_cast<const short8*>(
          &K[base + (size_t)(n * 16 + fl) * 64 + ks * 32 + kq]);

  f32x4 sacc[4];
#pragma unroll
  for (int n = 0; n < 4; ++n) sacc[n] = (f32x4)0.f;
#pragma unroll
  for (int n = 0; n < 4; ++n)
#pragma unroll
    for (int ks = 0; ks < 2; ++ks)
      sacc[n] = __builtin_amdgcn_mfma_f32_16x16x32_bf16(aq[ks], bk[n][ks],
                                                        sacc[n], 0, 0, 0);

  float recip[4];
  float ex[4][4];
#pragma unroll
  for (int r = 0; r < 4; ++r) {
    float mx = fmaxf(fmaxf(sacc[0][r], sacc[1][r]), fmaxf(sacc[2][r], sacc[3][r]));
    mx = fmaxf(mx, __shfl_xor(mx, 1, 64));
    mx = fmaxf(mx, __shfl_xor(mx, 2, 64));
    mx = fmaxf(mx, __shfl_xor(mx, 4, 64));
    mx = fmaxf(mx, __shfl_xor(mx, 8, 64));
    float sum = 0.f;
#pragma unroll
    for (int n = 0; n < 4; ++n) {
      ex[n][r] = __expf(sacc[n][r] - mx);
      sum += ex[n][r];
    }
    sum += __shfl_xor(sum, 1, 64);
    sum += __shfl_xor(sum, 2, 64);
    sum += __shfl_xor(sum, 4, 64);
    sum += __shfl_xor(sum, 8, 64);
    recip[r] = 1.f / sum;
  }

#pragma unroll
  for (int n = 0; n < 4; ++n)
#pragma unroll
    for (int r = 0; r < 4; ++r)
      P[wave][g4 * 4 + r][n * 16 + fl] = __float2bfloat16(ex[n][r]);

  __syncthreads();

  short8 ap[2];
#pragma unroll
  for (int ks = 0; ks < 2; ++ks)
    ap[ks] = *reinterpret_cast<const short8*>(&P[wave][fl][ks * 32 + kq]);
  short8 bv[4][2];
#pragma unroll
  for (int n = 0; n < 4; ++n)
#pragma unroll
    for (int ks = 0; ks < 2; ++ks)
      bv[n][ks] = *reinterpret_cast<const short8*>(&Vt[n * 16 + fl][ks * 32 + kq]);

  f32x4 oacc[4];
#pragma unroll
  for (int n = 0; n < 4; ++n) oacc[n] = (f32x4)0.f;
#pragma unroll
  for (int n = 0; n < 4; ++n)
#pragma unroll
    for (int ks = 0; ks < 2; ++ks)
      oacc[n] = __builtin_amdgcn_mfma_f32_16x16x32_bf16(ap[ks], bv[n][ks],
                                                        oacc[n], 0, 0, 0);

  float mkvc[4];
#pragma unroll
  for (int n = 0; n < 4; ++n) {
    const int d = n * 16 + fl;
    mkvc[n] = 1.f / (1.f + __expf(-(mu_kv[d] + eps_kv[d] * sigma_kv[d])));
  }
#pragma unroll
  for (int n = 0; n < 4; ++n) {
    const int d = n * 16 + fl;
#pragma unroll
    for (int r = 0; r < 4; ++r) {
      const int h = wave * 16 + g4 * 4 + r;
      AO[base + (size_t)h * 64 + d] =
          __float2bfloat16(oacc[n][r] * recip[r] * mkvc[n]);
    }
  }
}

// ---------------- launch ----------------
extern "C" void kernel_launch(void* const* d_in, const int* in_sizes, int n_in,
                              void* d_out, int out_size, void* d_ws, size_t ws_size,
                              hipStream_t stream) {
  (void)in_sizes; (void)n_in; (void)out_size; (void)ws_size;
  const float* X        = (const float*)d_in[0];
  const float* Wq       = (const float*)d_in[1];
  const float* Wk       = (const float*)d_in[2];
  const float* Wv       = (const float*)d_in[3];
  const float* Wo       = (const float*)d_in[4];
  const float* mu_q     = (const float*)d_in[5];
  const float* sigma_q  = (const float*)d_in[6];
  const float* mu_kv    = (const float*)d_in[7];
  const float* sigma_kv = (const float*)d_in[8];
  const float* eps_q    = (const float*)d_in[9];
  const float* eps_kv   = (const float*)d_in[10];
  float* out = (float*)d_out;

  const int M = 8192, N = 4096, Kd = 4096;

  char* ws = (char*)d_ws;
  bf16* Xb = (bf16*)(ws);                              // 64 MiB (reused as AO)
  bf16* Wb = (bf16*)(ws + (size_t)64  * (1u << 20));   // 32 MiB shared W buffer
  bf16* Qb = (bf16*)(ws + (size_t)96  * (1u << 20));   // 64 MiB
  bf16* Kb = (bf16*)(ws + (size_t)160 * (1u << 20));   // 64 MiB
  bf16* Vb = (bf16*)(ws + (size_t)224 * (1u << 20));   // 64 MiB  (total 288 MiB)

  const int LDS_BYTES = 65536;
  hipFuncSetAttribute(reinterpret_cast<const void*>(&gemm256<bf16, false>),
                      hipFuncAttributeMaxDynamicSharedMemorySize, LDS_BYTES);
  hipFuncSetAttribute(reinterpret_cast<const void*>(&gemm256<bf16, true>),
                      hipFuncAttributeMaxDynamicSharedMemorySize, LDS_BYTES);
  hipFuncSetAttribute(reinterpret_cast<const void*>(&gemm256<float, false>),
                      hipFuncAttributeMaxDynamicSharedMemorySize, LDS_BYTES);

  const dim3 blk(256);
  const dim3 blk512(512);
  const dim3 cgrid(2048);
  const dim3 ggrid((M / 256) * (N / 256));             // 512 blocks

  cast_f32_to_bf16<<<cgrid, blk, 0, stream>>>(X, Xb, M * Kd);

  cast_f32_to_bf16<<<cgrid, blk, 0, stream>>>(Wq, Wb, N * Kd);
  gemm256<bf16, false><<<ggrid, blk512, LDS_BYTES, stream>>>(Xb, Wb, Qb, M, N, Kd,
      nullptr, nullptr, nullptr, nullptr, nullptr, nullptr);

  cast_f32_to_bf16<<<cgrid, blk, 0, stream>>>(Wk, Wb, N * Kd);
  gemm256<bf16, true><<<ggrid, blk512, LDS_BYTES, stream>>>(Xb, Wb, Kb, M, N, Kd,
      mu_q, sigma_q, eps_q, mu_kv, sigma_kv, eps_kv);

  cast_f32_to_bf16<<<cgrid, blk, 0, stream>>>(Wv, Wb, N * Kd);
  gemm256<bf16, false><<<ggrid, blk512, LDS_BYTES, stream>>>(Xb, Wb, Vb, M, N, Kd,
      nullptr, nullptr, nullptr, nullptr, nullptr, nullptr);

  bf16* AO = Xb;  // X no longer needed
  attn_mfma<<<dim3(M), blk, 0, stream>>>(Qb, Kb, Vb, mu_kv, sigma_kv, eps_kv, AO);

  cast_f32_to_bf16<<<cgrid, blk, 0, stream>>>(Wo, Wb, N * Kd);
  gemm256<float, false><<<ggrid, blk512, LDS_BYTES, stream>>>(AO, Wb, out, M, N, Kd,
      nullptr, nullptr, nullptr, nullptr, nullptr, nullptr);
}

// Round 8
// 1241.105 us; speedup vs baseline: 1.2675x; 1.2675x over previous
//
#include <hip/hip_runtime.h>
#include <hip/hip_bf16.h>

using bf16 = __hip_bfloat16;
typedef __attribute__((ext_vector_type(8))) short short8;
typedef __attribute__((ext_vector_type(4))) float f32x4;
typedef __attribute__((ext_vector_type(16))) float f32x16;

#define GAS(p) ((const __attribute__((address_space(1))) unsigned int*)(p))
#define LAS(p) ((__attribute__((address_space(3))) unsigned int*)(p))

// ---------------- cast f32 -> bf16 (vectorized) ----------------
__global__ __launch_bounds__(256)
void cast_f32_to_bf16(const float* __restrict__ in, bf16* __restrict__ out, int n) {
  const int stride = gridDim.x * blockDim.x * 4;
  for (int i = (blockIdx.x * blockDim.x + threadIdx.x) * 4; i < n; i += stride) {
    float4 v = *reinterpret_cast<const float4*>(in + i);
    bf16 b0 = __float2bfloat16(v.x);
    bf16 b1 = __float2bfloat16(v.y);
    bf16 b2 = __float2bfloat16(v.z);
    bf16 b3 = __float2bfloat16(v.w);
    ushort4 p;
    p.x = *reinterpret_cast<unsigned short*>(&b0);
    p.y = *reinterpret_cast<unsigned short*>(&b1);
    p.z = *reinterpret_cast<unsigned short*>(&b2);
    p.w = *reinterpret_cast<unsigned short*>(&b3);
    *reinterpret_cast<ushort4*>(out + i) = p;
  }
}

// ================= 256x256 NT GEMM, mfma 32x32x16, A+B in LDS =================
// C[M,N] = A[M,K]*B[N,K]^T.  512 thr (8 waves, 2M x 4N), BK=64, 128 KiB LDS.
// Both A and B staged with IDENTICAL row-grouped layout (group q = row bit6,
// j-half = row bit7; [128 rows][128B] per 16KB group; 3-bit XOR swizzle on
// 16B-slot keyed on row bits 1-3 = rl bits 1-3; global source pre-swizzled).
// MFMA 32x32x16 (4060 FLOP/cyc vs 3378 for 16x16 — R7-verified layouts).
// Wave tile 128x64: m-frags 4 (gA=m>>1, lr=wm*64+(m&1)*32+rl),
//                   n-frags 2 (gB=wn&1, lr=(wn>>1)*64+n*32+rl).
// 2 phases/tile, ledger (8 DMA loads/tile, order Bq0,Bq1,Aq0,Aq1):
//  H1: vmcnt(0) [drains 2 stale Aq1-loads] +bar; read bf0,bf1,af23(cur);
//      stage all 8 (t+1,nxt); 16 MFMA af01 x bf.
//  H2: vmcnt(2) [drains B+Aq0 of t+1] +bar; read af01(nxt); 16 MFMA af23 x bf.
// Register liveness: af01 dies in H1, bf/af23 die in H2 -> no reg dbuf needed.
template <typename OutT, bool KMASK>
__global__ __launch_bounds__(512, 2)
void gemm256(const bf16* __restrict__ A, const bf16* __restrict__ B,
             OutT* __restrict__ C, int M, int N, int K,
             const float* __restrict__ mu_q, const float* __restrict__ sigma_q,
             const float* __restrict__ eps_q,
             const float* __restrict__ mu_kv, const float* __restrict__ sigma_kv,
             const float* __restrict__ eps_kv) {
  extern __shared__ char smem[];   // [0,64K): A buf0,buf1 ; [64K,128K): B buf0,buf1

  const int nwg = gridDim.x;
  const int cpx = nwg >> 3;
  const int bid = blockIdx.x;
  const int swz = (bid & 7) * cpx + (bid >> 3);
  const int ntn = N >> 8;
  const int tm = swz / ntn, tn = swz % ntn;
  const int row0 = tm << 8, col0 = tn << 8;

  const int t = threadIdx.x;
  const int wave = t >> 6, lane = t & 63;
  const int wm = wave >> 2, wn = wave & 3;   // 2 x 4 wave grid
  const int rl = lane & 31;                  // mfma row within 32
  const int h  = lane >> 5;                  // k-half select
  const int ldsWave = wave << 10;

  // ---- staging: per-thread global source (inverse swizzle, in elems) ----
  const int srow = t >> 3;                                  // 0..63
  const int scol = ((t & 7) * 8) ^
                   (((srow & 2) << 4) | ((srow & 4) << 2) | (srow & 8));
  size_t aRow[2][2], bRow[2][2];                            // [q][j]
#pragma unroll
  for (int q = 0; q < 2; ++q)
#pragma unroll
    for (int j = 0; j < 2; ++j) {
      aRow[q][j] = (size_t)(row0 + j * 128 + q * 64 + srow) * K + scol;
      bRow[q][j] = (size_t)(col0 + j * 128 + q * 64 + srow) * K + scol;
    }

  // ---- read constants (R7-verified swizzle, keyed on rl bits 1-3) ----
  const int xsw = ((rl & 2) << 5) | ((rl & 4) << 3) | ((rl & 8) << 1);
  int koff[4];
#pragma unroll
  for (int ks = 0; ks < 4; ++ks) koff[ks] = (ks * 32 + h * 16) ^ xsw;
  const int lrA0 = wm * 64 + rl;            // m&1==0 rows
  const int lrA1 = wm * 64 + 32 + rl;       // m&1==1 rows
  const int bBase = 65536 + (wn & 1) * 16384;
  const int lrB0 = (wn >> 1) * 64 + rl;     // n==0
  const int lrB1 = (wn >> 1) * 64 + 32 + rl;// n==1

  f32x16 acc[4][2];
#pragma unroll
  for (int m = 0; m < 4; ++m)
#pragma unroll
    for (int n = 0; n < 2; ++n) acc[m][n] = (f32x16)0.f;

// 8 loads, order: Bq0(2), Bq1(2), Aq0(2), Aq1(2)
#define STG_ALL(buf_, kk_) do {                                               \
    _Pragma("unroll")                                                         \
    for (int q = 0; q < 2; ++q)                                               \
      _Pragma("unroll")                                                       \
      for (int j = 0; j < 2; ++j)                                             \
        __builtin_amdgcn_global_load_lds(GAS(B + bRow[q][j] + (kk_)),         \
            LAS(smem + 65536 + (buf_) * 32768 + q * 16384 + j * 8192 +        \
                ldsWave), 16, 0, 0);                                          \
    _Pragma("unroll")                                                         \
    for (int q = 0; q < 2; ++q)                                               \
      _Pragma("unroll")                                                       \
      for (int j = 0; j < 2; ++j)                                             \
        __builtin_amdgcn_global_load_lds(GAS(A + aRow[q][j] + (kk_)),         \
            LAS(smem + (buf_) * 32768 + q * 16384 + j * 8192 + ldsWave),      \
            16, 0, 0);                                                       \
  } while (0)

  const int NT = K >> 6;
  short8 af01[2][4], af23[2][4], bf0[4], bf1[4];

  // prologue: tile 0 -> buf0; pre-read af01(0)
  STG_ALL(0, 0);
  asm volatile("s_waitcnt vmcnt(2)" ::: "memory");   // B(0)+Aq0(0) arrived
  __builtin_amdgcn_s_barrier();
  asm volatile("" ::: "memory");
#pragma unroll
  for (int mm = 0; mm < 2; ++mm) {
    const int lr = (mm == 0) ? lrA0 : lrA1;
#pragma unroll
    for (int ks = 0; ks < 4; ++ks)
      af01[mm][ks] = *reinterpret_cast<const short8*>(smem + lr * 128 + koff[ks]);
  }

  for (int tt = 0; tt < NT; ++tt) {
    const int cur = tt & 1, nxt = cur ^ 1;
    const size_t kkn = (size_t)((tt + 1 < NT) ? ((tt + 1) << 6) : 0);
    const char* aCur = smem + cur * 32768;
    const char* bCur = smem + bBase + cur * 32768;
    const char* aNxt = smem + nxt * 32768;

    // ---- H1: MFMA af01 x bf ; read bf(cur), af23(cur); stage tile t+1 ----
    asm volatile("s_waitcnt vmcnt(0)" ::: "memory");   // 2 stale Aq1 loads
    __builtin_amdgcn_s_barrier();
    asm volatile("" ::: "memory");
#pragma unroll
    for (int ks = 0; ks < 4; ++ks) {
      bf0[ks] = *reinterpret_cast<const short8*>(bCur + lrB0 * 128 + koff[ks]);
      bf1[ks] = *reinterpret_cast<const short8*>(bCur + lrB1 * 128 + koff[ks]);
    }
#pragma unroll
    for (int mm = 0; mm < 2; ++mm) {
      const int lr = (mm == 0) ? lrA0 : lrA1;
#pragma unroll
      for (int ks = 0; ks < 4; ++ks)
        af23[mm][ks] = *reinterpret_cast<const short8*>(
            aCur + 16384 + lr * 128 + koff[ks]);
    }
    STG_ALL(nxt, kkn);
    __builtin_amdgcn_s_setprio(1);
#pragma unroll
    for (int mm = 0; mm < 2; ++mm)
#pragma unroll
      for (int ks = 0; ks < 4; ++ks) {
        acc[mm][0] = __builtin_amdgcn_mfma_f32_32x32x16_bf16(
            af01[mm][ks], bf0[ks], acc[mm][0], 0, 0, 0);
        acc[mm][1] = __builtin_amdgcn_mfma_f32_32x32x16_bf16(
            af01[mm][ks], bf1[ks], acc[mm][1], 0, 0, 0);
      }
    __builtin_amdgcn_s_setprio(0);

    // ---- H2: MFMA af23 x bf ; read af01 <- buf nxt (tile t+1, group 0) ----
    asm volatile("s_waitcnt vmcnt(2)" ::: "memory");   // B(t+1)+Aq0(t+1) arrived
    __builtin_amdgcn_s_barrier();
    asm volatile("" ::: "memory");
#pragma unroll
    for (int mm = 0; mm < 2; ++mm) {
      const int lr = (mm == 0) ? lrA0 : lrA1;
#pragma unroll
      for (int ks = 0; ks < 4; ++ks)
        af01[mm][ks] = *reinterpret_cast<const short8*>(
            aNxt + lr * 128 + koff[ks]);
    }
    __builtin_amdgcn_s_setprio(1);
#pragma unroll
    for (int mm = 0; mm < 2; ++mm)
#pragma unroll
      for (int ks = 0; ks < 4; ++ks) {
        acc[2 + mm][0] = __builtin_amdgcn_mfma_f32_32x32x16_bf16(
            af23[mm][ks], bf0[ks], acc[2 + mm][0], 0, 0, 0);
        acc[2 + mm][1] = __builtin_amdgcn_mfma_f32_32x32x16_bf16(
            af23[mm][ks], bf1[ks], acc[2 + mm][1], 0, 0, 0);
      }
    __builtin_amdgcn_s_setprio(0);
  }
#undef STG_ALL

  asm volatile("s_waitcnt vmcnt(0)" ::: "memory");

  // ---- epilogue: 32x32 C/D layout (R7-verified):
  //      col = lane&31, row = (reg&3) + 8*(reg>>2) + 4*(lane>>5) ----
  const int crow0 = row0 + wm * 128 + 4 * h;
  const int ccol0 = col0 + wn * 64 + rl;
  float cscale[2];
  if constexpr (KMASK) {
#pragma unroll
    for (int n = 0; n < 2; ++n) {
      const int d = (ccol0 + n * 32) & 63;
      const float a = mu_q[d] + eps_q[d] * sigma_q[d];
      const float b = mu_kv[d] + eps_kv[d] * sigma_kv[d];
      cscale[n] = 0.125f / ((1.f + __expf(-a)) * (1.f + __expf(-b)));
    }
  }
#pragma unroll
  for (int m = 0; m < 4; ++m) {
#pragma unroll
    for (int n = 0; n < 2; ++n) {
      const int cc = ccol0 + n * 32;
#pragma unroll
      for (int rg = 0; rg < 4; ++rg) {
#pragma unroll
        for (int rr = 0; rr < 4; ++rr) {
          const int row = crow0 + m * 32 + rg * 8 + rr;
          float v = acc[m][n][rg * 4 + rr];
          if constexpr (KMASK) v *= cscale[n];
          if constexpr (sizeof(OutT) == 2) {
            C[(size_t)row * N + cc] = __float2bfloat16(v);
          } else {
            C[(size_t)row * N + cc] = v;
          }
        }
      }
    }
  }
}

// ---------------- per-token cross-head attention, MFMA ----------------
__global__ __launch_bounds__(256)
void attn_mfma(const bf16* __restrict__ Q, const bf16* __restrict__ K,
               const bf16* __restrict__ V,
               const float* __restrict__ mu_kv, const float* __restrict__ sigma_kv,
               const float* __restrict__ eps_kv,
               bf16* __restrict__ AO) {
  __shared__ bf16 Vt[64][72];
  __shared__ bf16 P[4][16][72];

  const int t = threadIdx.x;
  const int wave = t >> 6, lane = t & 63;
  const int fl = lane & 15, g4 = lane >> 4;
  const int kq = g4 * 8;
  const size_t base = (size_t)blockIdx.x * 4096;

#pragma unroll
  for (int rep = 0; rep < 2; ++rep) {
    const int idx = rep * 256 + t;
    const int g = idx & 63;
    const int d0 = (idx >> 6) * 8;
    short8 v8 = *reinterpret_cast<const short8*>(&V[base + (size_t)g * 64 + d0]);
#pragma unroll
    for (int j = 0; j < 8; ++j)
      *reinterpret_cast<short*>(&Vt[d0 + j][g]) = (short)v8[j];
  }

  short8 aq[2];
#pragma unroll
  for (int ks = 0; ks < 2; ++ks)
    aq[ks] = *reinterpret_cast<const short8*>(
        &Q[base + (size_t)(wave * 16 + fl) * 64 + ks * 32 + kq]);
  short8 bk[4][2];
#pragma unroll
  for (int n = 0; n < 4; ++n)
#pragma unroll
    for (int ks = 0; ks < 2; ++ks)
      bk[n][ks] = *reinterpret_cast<const short8*>(
          &K[base + (size_t)(n * 16 + fl) * 64 + ks * 32 + kq]);

  f32x4 sacc[4];
#pragma unroll
  for (int n = 0; n < 4; ++n) sacc[n] = (f32x4)0.f;
#pragma unroll
  for (int n = 0; n < 4; ++n)
#pragma unroll
    for (int ks = 0; ks < 2; ++ks)
      sacc[n] = __builtin_amdgcn_mfma_f32_16x16x32_bf16(aq[ks], bk[n][ks],
                                                        sacc[n], 0, 0, 0);

  float recip[4];
  float ex[4][4];
#pragma unroll
  for (int r = 0; r < 4; ++r) {
    float mx = fmaxf(fmaxf(sacc[0][r], sacc[1][r]), fmaxf(sacc[2][r], sacc[3][r]));
    mx = fmaxf(mx, __shfl_xor(mx, 1, 64));
    mx = fmaxf(mx, __shfl_xor(mx, 2, 64));
    mx = fmaxf(mx, __shfl_xor(mx, 4, 64));
    mx = fmaxf(mx, __shfl_xor(mx, 8, 64));
    float sum = 0.f;
#pragma unroll
    for (int n = 0; n < 4; ++n) {
      ex[n][r] = __expf(sacc[n][r] - mx);
      sum += ex[n][r];
    }
    sum += __shfl_xor(sum, 1, 64);
    sum += __shfl_xor(sum, 2, 64);
    sum += __shfl_xor(sum, 4, 64);
    sum += __shfl_xor(sum, 8, 64);
    recip[r] = 1.f / sum;
  }

#pragma unroll
  for (int n = 0; n < 4; ++n)
#pragma unroll
    for (int r = 0; r < 4; ++r)
      P[wave][g4 * 4 + r][n * 16 + fl] = __float2bfloat16(ex[n][r]);

  __syncthreads();

  short8 ap[2];
#pragma unroll
  for (int ks = 0; ks < 2; ++ks)
    ap[ks] = *reinterpret_cast<const short8*>(&P[wave][fl][ks * 32 + kq]);
  short8 bv[4][2];
#pragma unroll
  for (int n = 0; n < 4; ++n)
#pragma unroll
    for (int ks = 0; ks < 2; ++ks)
      bv[n][ks] = *reinterpret_cast<const short8*>(&Vt[n * 16 + fl][ks * 32 + kq]);

  f32x4 oacc[4];
#pragma unroll
  for (int n = 0; n < 4; ++n) oacc[n] = (f32x4)0.f;
#pragma unroll
  for (int n = 0; n < 4; ++n)
#pragma unroll
    for (int ks = 0; ks < 2; ++ks)
      oacc[n] = __builtin_amdgcn_mfma_f32_16x16x32_bf16(ap[ks], bv[n][ks],
                                                        oacc[n], 0, 0, 0);

  float mkvc[4];
#pragma unroll
  for (int n = 0; n < 4; ++n) {
    const int d = n * 16 + fl;
    mkvc[n] = 1.f / (1.f + __expf(-(mu_kv[d] + eps_kv[d] * sigma_kv[d])));
  }
#pragma unroll
  for (int n = 0; n < 4; ++n) {
    const int d = n * 16 + fl;
#pragma unroll
    for (int r = 0; r < 4; ++r) {
      const int h = wave * 16 + g4 * 4 + r;
      AO[base + (size_t)h * 64 + d] =
          __float2bfloat16(oacc[n][r] * recip[r] * mkvc[n]);
    }
  }
}

// ---------------- launch ----------------
extern "C" void kernel_launch(void* const* d_in, const int* in_sizes, int n_in,
                              void* d_out, int out_size, void* d_ws, size_t ws_size,
                              hipStream_t stream) {
  (void)in_sizes; (void)n_in; (void)out_size; (void)ws_size;
  const float* X        = (const float*)d_in[0];
  const float* Wq       = (const float*)d_in[1];
  const float* Wk       = (const float*)d_in[2];
  const float* Wv       = (const float*)d_in[3];
  const float* Wo       = (const float*)d_in[4];
  const float* mu_q     = (const float*)d_in[5];
  const float* sigma_q  = (const float*)d_in[6];
  const float* mu_kv    = (const float*)d_in[7];
  const float* sigma_kv = (const float*)d_in[8];
  const float* eps_q    = (const float*)d_in[9];
  const float* eps_kv   = (const float*)d_in[10];
  float* out = (float*)d_out;

  const int M = 8192, N = 4096, Kd = 4096;

  char* ws = (char*)d_ws;
  bf16* Xb = (bf16*)(ws);                              // 64 MiB (reused as AO)
  bf16* Wb = (bf16*)(ws + (size_t)64  * (1u << 20));   // 32 MiB shared W buffer
  bf16* Qb = (bf16*)(ws + (size_t)96  * (1u << 20));   // 64 MiB
  bf16* Kb = (bf16*)(ws + (size_t)160 * (1u << 20));   // 64 MiB
  bf16* Vb = (bf16*)(ws + (size_t)224 * (1u << 20));   // 64 MiB  (total 288 MiB)

  const int LDS_BYTES = 131072;
  hipFuncSetAttribute(reinterpret_cast<const void*>(&gemm256<bf16, false>),
                      hipFuncAttributeMaxDynamicSharedMemorySize, LDS_BYTES);
  hipFuncSetAttribute(reinterpret_cast<const void*>(&gemm256<bf16, true>),
                      hipFuncAttributeMaxDynamicSharedMemorySize, LDS_BYTES);
  hipFuncSetAttribute(reinterpret_cast<const void*>(&gemm256<float, false>),
                      hipFuncAttributeMaxDynamicSharedMemorySize, LDS_BYTES);

  const dim3 blk(256);
  const dim3 blk512(512);
  const dim3 cgrid(2048);
  const dim3 ggrid((M / 256) * (N / 256));             // 512 blocks

  cast_f32_to_bf16<<<cgrid, blk, 0, stream>>>(X, Xb, M * Kd);

  cast_f32_to_bf16<<<cgrid, blk, 0, stream>>>(Wq, Wb, N * Kd);
  gemm256<bf16, false><<<ggrid, blk512, LDS_BYTES, stream>>>(Xb, Wb, Qb, M, N, Kd,
      nullptr, nullptr, nullptr, nullptr, nullptr, nullptr);

  cast_f32_to_bf16<<<cgrid, blk, 0, stream>>>(Wk, Wb, N * Kd);
  gemm256<bf16, true><<<ggrid, blk512, LDS_BYTES, stream>>>(Xb, Wb, Kb, M, N, Kd,
      mu_q, sigma_q, eps_q, mu_kv, sigma_kv, eps_kv);

  cast_f32_to_bf16<<<cgrid, blk, 0, stream>>>(Wv, Wb, N * Kd);
  gemm256<bf16, false><<<ggrid, blk512, LDS_BYTES, stream>>>(Xb, Wb, Vb, M, N, Kd,
      nullptr, nullptr, nullptr, nullptr, nullptr, nullptr);

  bf16* AO = Xb;  // X no longer needed
  attn_mfma<<<dim3(M), blk, 0, stream>>>(Qb, Kb, Vb, mu_kv, sigma_kv, eps_kv, AO);

  cast_f32_to_bf16<<<cgrid, blk, 0, stream>>>(Wo, Wb, N * Kd);
  gemm256<float, false><<<ggrid, blk512, LDS_BYTES, stream>>>(AO, Wb, out, M, N, Kd,
      nullptr, nullptr, nullptr, nullptr, nullptr, nullptr);
}

// Round 9
// 1158.569 us; speedup vs baseline: 1.3578x; 1.0712x over previous
//
#include <hip/hip_runtime.h>
#include <hip/hip_bf16.h>

using bf16 = __hip_bfloat16;
typedef __attribute__((ext_vector_type(8))) short short8;
typedef __attribute__((ext_vector_type(4))) float f32x4;

#define GAS(p) ((const __attribute__((address_space(1))) unsigned int*)(p))
#define LAS(p) ((__attribute__((address_space(3))) unsigned int*)(p))

// ---------------- cast f32 -> bf16 (vectorized) ----------------
__global__ __launch_bounds__(256)
void cast_f32_to_bf16(const float* __restrict__ in, bf16* __restrict__ out, int n) {
  const int stride = gridDim.x * blockDim.x * 4;
  for (int i = (blockIdx.x * blockDim.x + threadIdx.x) * 4; i < n; i += stride) {
    float4 v = *reinterpret_cast<const float4*>(in + i);
    bf16 b0 = __float2bfloat16(v.x);
    bf16 b1 = __float2bfloat16(v.y);
    bf16 b2 = __float2bfloat16(v.z);
    bf16 b3 = __float2bfloat16(v.w);
    ushort4 p;
    p.x = *reinterpret_cast<unsigned short*>(&b0);
    p.y = *reinterpret_cast<unsigned short*>(&b1);
    p.z = *reinterpret_cast<unsigned short*>(&b2);
    p.w = *reinterpret_cast<unsigned short*>(&b3);
    *reinterpret_cast<ushort4*>(out + i) = p;
  }
}

// ============ 256x256 NT GEMM — faithful m201-template port ============
// C[M,N] = A[M,K]*B[N,K]^T.  512 thr (8 waves, 2M x 4N), BK=64, 128 KiB LDS.
// LDS units per K-tile: Ak0,Ak1,Bk0,Bk1 — each [256 rows][32 k] = 16 KB with
// 64-B rows (k-half split). Fragment reads (16 rows x 4 slots) hit all 8
// bank-quads uniformly -> conflict-free BY CONSTRUCTION; DMA dest linear.
// Phase skeleton (4 phases/K-tile, phase = (k-half a, n-half b)):
//   [pre-barrier: ds_read this phase's frags | optional vmcnt | stage 1 unit]
//   s_barrier ; lgkmcnt(0)+sched_barrier ; setprio(1) 16 MFMA setprio(0) ; s_barrier
// Reads issue BEFORE the barrier -> latency hides under barrier-wait; each
// unit is validated (vmcnt+barrier) one phase before its first read:
//   P01: vmcnt(2) validates Ak1(t),Bk1(t)  (read at P10)
//   P11: vmcnt(2) validates Ak0(t+1),Bk0(t+1) (read at P00(t+1))
// FIFO (2 loads/unit, issue order Ak0,Bk0,Ak1,Bk1): floor 2 in flight,
// issue->validate >= 2 phases. Dbuf => WAR safe (reads lgkm-complete before
// each phase's 2nd barrier; overwrite issues only after a later barrier).
template <typename OutT, bool KMASK>
__global__ __launch_bounds__(512, 2)
void gemm256(const bf16* __restrict__ A, const bf16* __restrict__ B,
             OutT* __restrict__ C, int M, int N, int K,
             const float* __restrict__ mu_q, const float* __restrict__ sigma_q,
             const float* __restrict__ eps_q,
             const float* __restrict__ mu_kv, const float* __restrict__ sigma_kv,
             const float* __restrict__ eps_kv) {
  extern __shared__ char smem[];   // buf b at b*65536: Ak0|Ak1|Bk0|Bk1 x16KB

  const int nwg = gridDim.x;
  const int cpx = nwg >> 3;
  const int bid = blockIdx.x;
  const int swz = (bid & 7) * cpx + (bid >> 3);
  const int ntn = N >> 8;
  const int tm = swz / ntn, tn = swz % ntn;
  const int row0 = tm << 8, col0 = tn << 8;

  const int t = threadIdx.x;
  const int wave = t >> 6, lane = t & 63;
  const int wm = wave >> 2, wn = wave & 3;   // 2 x 4 wave grid
  const int fl = lane & 15, g4 = lane >> 4;

  // ---- staging source (per-thread): row = srow, k-bytes (t&3)*16 ----
  const int srow = t >> 2;                   // 0..127
  const int skoff = (t & 3) * 8;             // elems
  const size_t aSrc0 = (size_t)(row0 + srow) * K + skoff;
  const size_t aSrc1 = (size_t)(row0 + 128 + srow) * K + skoff;
  const size_t bSrc0 = (size_t)(col0 + srow) * K + skoff;
  const size_t bSrc1 = (size_t)(col0 + 128 + srow) * K + skoff;
  const int t16 = t * 16;

  // ---- fragment read bases (byte offsets inside a 16KB unit) ----
  const int aoff0 = (wm * 128 + fl) * 64 + g4 * 16;   // + m*1024
  const int boff0 = (wn * 64 + fl) * 64 + g4 * 16;    // + n*1024

  f32x4 acc[8][4];
#pragma unroll
  for (int m = 0; m < 8; ++m)
#pragma unroll
    for (int n = 0; n < 4; ++n) acc[m][n] = (f32x4)0.f;

#define STG_A(buf_, kh_, kk_) do {                                            \
    __builtin_amdgcn_global_load_lds(GAS(A + aSrc0 + (kk_) + (kh_) * 32),     \
        LAS(smem + (buf_) * 65536 + (kh_) * 16384 + t16), 16, 0, 0);          \
    __builtin_amdgcn_global_load_lds(GAS(A + aSrc1 + (kk_) + (kh_) * 32),     \
        LAS(smem + (buf_) * 65536 + (kh_) * 16384 + 8192 + t16), 16, 0, 0);   \
  } while (0)
#define STG_B(buf_, kh_, kk_) do {                                            \
    __builtin_amdgcn_global_load_lds(GAS(B + bSrc0 + (kk_) + (kh_) * 32),     \
        LAS(smem + (buf_) * 65536 + 32768 + (kh_) * 16384 + t16), 16, 0, 0);  \
    __builtin_amdgcn_global_load_lds(GAS(B + bSrc1 + (kk_) + (kh_) * 32),     \
        LAS(smem + (buf_) * 65536 + 32768 + (kh_) * 16384 + 8192 + t16),      \
        16, 0, 0);                                                            \
  } while (0)

  const int NT = K >> 6;

  // ---- prologue: tile 0, issue order Ak0,Bk0,Ak1,Bk1; validate Ak0,Bk0 ----
  STG_A(0, 0, 0); STG_B(0, 0, 0); STG_A(0, 1, 0); STG_B(0, 1, 0);
  asm volatile("s_waitcnt vmcnt(4)" ::: "memory");
  __builtin_amdgcn_s_barrier();
  asm volatile("" ::: "memory");

  short8 af[8], bf[2];

  for (int tt = 0; tt < NT; ++tt) {
    const int cur = tt & 1, nxt = cur ^ 1;
    const size_t kkn = (size_t)((tt + 1 < NT) ? ((tt + 1) << 6) : 0);
    const char* aU0 = smem + cur * 65536;            // Ak0
    const char* aU1 = aU0 + 16384;                   // Ak1
    const char* bU0 = aU0 + 32768;                   // Bk0
    const char* bU1 = aU0 + 49152;                   // Bk1

    // ================ P00 (a=0, b=0) ================
#pragma unroll
    for (int m = 0; m < 8; ++m)
      af[m] = *reinterpret_cast<const short8*>(aU0 + aoff0 + m * 1024);
    bf[0] = *reinterpret_cast<const short8*>(bU0 + boff0);
    bf[1] = *reinterpret_cast<const short8*>(bU0 + boff0 + 1024);
    STG_A(nxt, 0, kkn);
    asm volatile("" ::: "memory");
    __builtin_amdgcn_s_barrier();
    asm volatile("s_waitcnt lgkmcnt(0)" ::: "memory");
    __builtin_amdgcn_sched_barrier(0);
    __builtin_amdgcn_s_setprio(1);
#pragma unroll
    for (int m = 0; m < 8; ++m)
#pragma unroll
      for (int n = 0; n < 2; ++n)
        acc[m][n] = __builtin_amdgcn_mfma_f32_16x16x32_bf16(af[m], bf[n],
                                                            acc[m][n], 0, 0, 0);
    __builtin_amdgcn_s_setprio(0);
    __builtin_amdgcn_s_barrier();
    asm volatile("" ::: "memory");

    // ================ P01 (a=0, b=1) ================
    bf[0] = *reinterpret_cast<const short8*>(bU0 + boff0 + 2048);
    bf[1] = *reinterpret_cast<const short8*>(bU0 + boff0 + 3072);
    asm volatile("s_waitcnt vmcnt(2)" ::: "memory");   // validates Ak1(t),Bk1(t)
    STG_B(nxt, 0, kkn);
    asm volatile("" ::: "memory");
    __builtin_amdgcn_s_barrier();
    asm volatile("s_waitcnt lgkmcnt(0)" ::: "memory");
    __builtin_amdgcn_sched_barrier(0);
    __builtin_amdgcn_s_setprio(1);
#pragma unroll
    for (int m = 0; m < 8; ++m)
#pragma unroll
      for (int n = 0; n < 2; ++n)
        acc[m][2 + n] = __builtin_amdgcn_mfma_f32_16x16x32_bf16(af[m], bf[n],
                                                                acc[m][2 + n], 0, 0, 0);
    __builtin_amdgcn_s_setprio(0);
    __builtin_amdgcn_s_barrier();
    asm volatile("" ::: "memory");

    // ================ P10 (a=1, b=0) ================
#pragma unroll
    for (int m = 0; m < 8; ++m)
      af[m] = *reinterpret_cast<const short8*>(aU1 + aoff0 + m * 1024);
    bf[0] = *reinterpret_cast<const short8*>(bU1 + boff0);
    bf[1] = *reinterpret_cast<const short8*>(bU1 + boff0 + 1024);
    STG_A(nxt, 1, kkn);
    asm volatile("" ::: "memory");
    __builtin_amdgcn_s_barrier();
    asm volatile("s_waitcnt lgkmcnt(0)" ::: "memory");
    __builtin_amdgcn_sched_barrier(0);
    __builtin_amdgcn_s_setprio(1);
#pragma unroll
    for (int m = 0; m < 8; ++m)
#pragma unroll
      for (int n = 0; n < 2; ++n)
        acc[m][n] = __builtin_amdgcn_mfma_f32_16x16x32_bf16(af[m], bf[n],
                                                            acc[m][n], 0, 0, 0);
    __builtin_amdgcn_s_setprio(0);
    __builtin_amdgcn_s_barrier();
    asm volatile("" ::: "memory");

    // ================ P11 (a=1, b=1) ================
    bf[0] = *reinterpret_cast<const short8*>(bU1 + boff0 + 2048);
    bf[1] = *reinterpret_cast<const short8*>(bU1 + boff0 + 3072);
    asm volatile("s_waitcnt vmcnt(2)" ::: "memory");   // validates Ak0,Bk0(t+1)
    STG_B(nxt, 1, kkn);
    asm volatile("" ::: "memory");
    __builtin_amdgcn_s_barrier();
    asm volatile("s_waitcnt lgkmcnt(0)" ::: "memory");
    __builtin_amdgcn_sched_barrier(0);
    __builtin_amdgcn_s_setprio(1);
#pragma unroll
    for (int m = 0; m < 8; ++m)
#pragma unroll
      for (int n = 0; n < 2; ++n)
        acc[m][2 + n] = __builtin_amdgcn_mfma_f32_16x16x32_bf16(af[m], bf[n],
                                                                acc[m][2 + n], 0, 0, 0);
    __builtin_amdgcn_s_setprio(0);
    __builtin_amdgcn_s_barrier();
    asm volatile("" ::: "memory");
  }
#undef STG_A
#undef STG_B

  asm volatile("s_waitcnt vmcnt(0)" ::: "memory");

  // ---- epilogue: 16x16 C/D layout col=lane&15, row=(lane>>4)*4+reg ----
  const int crow0 = row0 + wm * 128 + g4 * 4;
  const int ccol0 = col0 + wn * 64 + fl;
  float cscale[4];
  if constexpr (KMASK) {
#pragma unroll
    for (int n = 0; n < 4; ++n) {
      const int d = (ccol0 + n * 16) & 63;
      const float a = mu_q[d] + eps_q[d] * sigma_q[d];
      const float b = mu_kv[d] + eps_kv[d] * sigma_kv[d];
      cscale[n] = 0.125f / ((1.f + __expf(-a)) * (1.f + __expf(-b)));
    }
  }
#pragma unroll
  for (int m = 0; m < 8; ++m) {
#pragma unroll
    for (int n = 0; n < 4; ++n) {
      const int cc = ccol0 + n * 16;
#pragma unroll
      for (int r = 0; r < 4; ++r) {
        const int rr = crow0 + m * 16 + r;
        float v = acc[m][n][r];
        if constexpr (KMASK) v *= cscale[n];
        if constexpr (sizeof(OutT) == 2) {
          C[(size_t)rr * N + cc] = __float2bfloat16(v);
        } else {
          C[(size_t)rr * N + cc] = v;
        }
      }
    }
  }
}

// ---------------- per-token cross-head attention, MFMA ----------------
__global__ __launch_bounds__(256)
void attn_mfma(const bf16* __restrict__ Q, const bf16* __restrict__ K,
               const bf16* __restrict__ V,
               const float* __restrict__ mu_kv, const float* __restrict__ sigma_kv,
               const float* __restrict__ eps_kv,
               bf16* __restrict__ AO) {
  __shared__ bf16 Vt[64][72];
  __shared__ bf16 P[4][16][72];

  const int t = threadIdx.x;
  const int wave = t >> 6, lane = t & 63;
  const int fl = lane & 15, g4 = lane >> 4;
  const int kq = g4 * 8;
  const size_t base = (size_t)blockIdx.x * 4096;

#pragma unroll
  for (int rep = 0; rep < 2; ++rep) {
    const int idx = rep * 256 + t;
    const int g = idx & 63;
    const int d0 = (idx >> 6) * 8;
    short8 v8 = *reinterpret_cast<const short8*>(&V[base + (size_t)g * 64 + d0]);
#pragma unroll
    for (int j = 0; j < 8; ++j)
      *reinterpret_cast<short*>(&Vt[d0 + j][g]) = (short)v8[j];
  }

  short8 aq[2];
#pragma unroll
  for (int ks = 0; ks < 2; ++ks)
    aq[ks] = *reinterpret_cast<const short8*>(
        &Q[base + (size_t)(wave * 16 + fl) * 64 + ks * 32 + kq]);
  short8 bk[4][2];
#pragma unroll
  for (int n = 0; n < 4; ++n)
#pragma unroll
    for (int ks = 0; ks < 2; ++ks)
      bk[n][ks] = *reinterpret_cast<const short8*>(
          &K[base + (size_t)(n * 16 + fl) * 64 + ks * 32 + kq]);

  f32x4 sacc[4];
#pragma unroll
  for (int n = 0; n < 4; ++n) sacc[n] = (f32x4)0.f;
#pragma unroll
  for (int n = 0; n < 4; ++n)
#pragma unroll
    for (int ks = 0; ks < 2; ++ks)
      sacc[n] = __builtin_amdgcn_mfma_f32_16x16x32_bf16(aq[ks], bk[n][ks],
                                                        sacc[n], 0, 0, 0);

  float recip[4];
  float ex[4][4];
#pragma unroll
  for (int r = 0; r < 4; ++r) {
    float mx = fmaxf(fmaxf(sacc[0][r], sacc[1][r]), fmaxf(sacc[2][r], sacc[3][r]));
    mx = fmaxf(mx, __shfl_xor(mx, 1, 64));
    mx = fmaxf(mx, __shfl_xor(mx, 2, 64));
    mx = fmaxf(mx, __shfl_xor(mx, 4, 64));
    mx = fmaxf(mx, __shfl_xor(mx, 8, 64));
    float sum = 0.f;
#pragma unroll
    for (int n = 0; n < 4; ++n) {
      ex[n][r] = __expf(sacc[n][r] - mx);
      sum += ex[n][r];
    }
    sum += __shfl_xor(sum, 1, 64);
    sum += __shfl_xor(sum, 2, 64);
    sum += __shfl_xor(sum, 4, 64);
    sum += __shfl_xor(sum, 8, 64);
    recip[r] = 1.f / sum;
  }

#pragma unroll
  for (int n = 0; n < 4; ++n)
#pragma unroll
    for (int r = 0; r < 4; ++r)
      P[wave][g4 * 4 + r][n * 16 + fl] = __float2bfloat16(ex[n][r]);

  __syncthreads();

  short8 ap[2];
#pragma unroll
  for (int ks = 0; ks < 2; ++ks)
    ap[ks] = *reinterpret_cast<const short8*>(&P[wave][fl][ks * 32 + kq]);
  short8 bv[4][2];
#pragma unroll
  for (int n = 0; n < 4; ++n)
#pragma unroll
    for (int ks = 0; ks < 2; ++ks)
      bv[n][ks] = *reinterpret_cast<const short8*>(&Vt[n * 16 + fl][ks * 32 + kq]);

  f32x4 oacc[4];
#pragma unroll
  for (int n = 0; n < 4; ++n) oacc[n] = (f32x4)0.f;
#pragma unroll
  for (int n = 0; n < 4; ++n)
#pragma unroll
    for (int ks = 0; ks < 2; ++ks)
      oacc[n] = __builtin_amdgcn_mfma_f32_16x16x32_bf16(ap[ks], bv[n][ks],
                                                        oacc[n], 0, 0, 0);

  float mkvc[4];
#pragma unroll
  for (int n = 0; n < 4; ++n) {
    const int d = n * 16 + fl;
    mkvc[n] = 1.f / (1.f + __expf(-(mu_kv[d] + eps_kv[d] * sigma_kv[d])));
  }
#pragma unroll
  for (int n = 0; n < 4; ++n) {
    const int d = n * 16 + fl;
#pragma unroll
    for (int r = 0; r < 4; ++r) {
      const int h = wave * 16 + g4 * 4 + r;
      AO[base + (size_t)h * 64 + d] =
          __float2bfloat16(oacc[n][r] * recip[r] * mkvc[n]);
    }
  }
}

// ---------------- launch ----------------
extern "C" void kernel_launch(void* const* d_in, const int* in_sizes, int n_in,
                              void* d_out, int out_size, void* d_ws, size_t ws_size,
                              hipStream_t stream) {
  (void)in_sizes; (void)n_in; (void)out_size; (void)ws_size;
  const float* X        = (const float*)d_in[0];
  const float* Wq       = (const float*)d_in[1];
  const float* Wk       = (const float*)d_in[2];
  const float* Wv       = (const float*)d_in[3];
  const float* Wo       = (const float*)d_in[4];
  const float* mu_q     = (const float*)d_in[5];
  const float* sigma_q  = (const float*)d_in[6];
  const float* mu_kv    = (const float*)d_in[7];
  const float* sigma_kv = (const float*)d_in[8];
  const float* eps_q    = (const float*)d_in[9];
  const float* eps_kv   = (const float*)d_in[10];
  float* out = (float*)d_out;

  const int M = 8192, N = 4096, Kd = 4096;

  char* ws = (char*)d_ws;
  bf16* Xb = (bf16*)(ws);                              // 64 MiB (reused as AO)
  bf16* Wb = (bf16*)(ws + (size_t)64  * (1u << 20));   // 32 MiB shared W buffer
  bf16* Qb = (bf16*)(ws + (size_t)96  * (1u << 20));   // 64 MiB
  bf16* Kb = (bf16*)(ws + (size_t)160 * (1u << 20));   // 64 MiB
  bf16* Vb = (bf16*)(ws + (size_t)224 * (1u << 20));   // 64 MiB  (total 288 MiB)

  const int LDS_BYTES = 131072;
  hipFuncSetAttribute(reinterpret_cast<const void*>(&gemm256<bf16, false>),
                      hipFuncAttributeMaxDynamicSharedMemorySize, LDS_BYTES);
  hipFuncSetAttribute(reinterpret_cast<const void*>(&gemm256<bf16, true>),
                      hipFuncAttributeMaxDynamicSharedMemorySize, LDS_BYTES);
  hipFuncSetAttribute(reinterpret_cast<const void*>(&gemm256<float, false>),
                      hipFuncAttributeMaxDynamicSharedMemorySize, LDS_BYTES);

  const dim3 blk(256);
  const dim3 blk512(512);
  const dim3 cgrid(2048);
  const dim3 ggrid((M / 256) * (N / 256));             // 512 blocks

  cast_f32_to_bf16<<<cgrid, blk, 0, stream>>>(X, Xb, M * Kd);

  cast_f32_to_bf16<<<cgrid, blk, 0, stream>>>(Wq, Wb, N * Kd);
  gemm256<bf16, false><<<ggrid, blk512, LDS_BYTES, stream>>>(Xb, Wb, Qb, M, N, Kd,
      nullptr, nullptr, nullptr, nullptr, nullptr, nullptr);

  cast_f32_to_bf16<<<cgrid, blk, 0, stream>>>(Wk, Wb, N * Kd);
  gemm256<bf16, true><<<ggrid, blk512, LDS_BYTES, stream>>>(Xb, Wb, Kb, M, N, Kd,
      mu_q, sigma_q, eps_q, mu_kv, sigma_kv, eps_kv);

  cast_f32_to_bf16<<<cgrid, blk, 0, stream>>>(Wv, Wb, N * Kd);
  gemm256<bf16, false><<<ggrid, blk512, LDS_BYTES, stream>>>(Xb, Wb, Vb, M, N, Kd,
      nullptr, nullptr, nullptr, nullptr, nullptr, nullptr);

  bf16* AO = Xb;  // X no longer needed
  attn_mfma<<<dim3(M), blk, 0, stream>>>(Qb, Kb, Vb, mu_kv, sigma_kv, eps_kv, AO);

  cast_f32_to_bf16<<<cgrid, blk, 0, stream>>>(Wo, Wb, N * Kd);
  gemm256<float, false><<<ggrid, blk512, LDS_BYTES, stream>>>(AO, Wb, out, M, N, Kd,
      nullptr, nullptr, nullptr, nullptr, nullptr, nullptr);
}